// Round 6
// baseline (615.328 us; speedup 1.0000x reference)
//
#include <hip/hip_runtime.h>

// ---------------------------------------------------------------------------
// HardwareOptimizedQuantumLLM  (B=4, S=1024, D=512, V=8192, SCALES={1,2,4,8,16}, WIN=8)
//
// R6: single fused k_resnet (3x [LN2 -> DxD GEMM -> residual gelu] + LN3) with
// x in C-layout registers, t in LDS, B streamed from L2. tanh folded into
// k_coh staging (phases buffer deleted). 8 dispatches total.
// ---------------------------------------------------------------------------

#define DEV __device__ __forceinline__
typedef unsigned short u16;
typedef __bf16 bf16x8 __attribute__((ext_vector_type(8)));
typedef float f32x4 __attribute__((ext_vector_type(4)));

static constexpr int S = 1024;
static constexpr int D = 512;
static constexpr int KCAT = 1056;   // 512 ctx + 512 lc + 5 msc + 1 sem + 1 const + 25 pad

DEV u16 f2bf(float f) {            // fp32 -> bf16 (RNE)
  unsigned u = __float_as_uint(f);
  return (u16)((u + 0x7fffu + ((u >> 16) & 1u)) >> 16);
}
DEV float gelu(float x) { return 0.5f * x * (1.f + erff(x * 0.70710678118654752f)); }
DEV float wred(float v) {
#pragma unroll
  for (int off = 32; off; off >>= 1) v += __shfl_down(v, off, 64);
  return v;
}
DEV void bred2(float& a, float& b, float* sm, int tid) {
  a = wred(a); b = wred(b);
  int w = tid >> 6;
  if ((tid & 63) == 0) { sm[w] = a; sm[w + 4] = b; }
  __syncthreads();
  a = sm[0] + sm[1] + sm[2] + sm[3];
  b = sm[4] + sm[5] + sm[6] + sm[7];
  __syncthreads();
}
DEV float qred(float v) {          // sum over quads (lanes x^1, x^2)
  v += __shfl_xor(v, 1, 64);
  v += __shfl_xor(v, 2, 64);
  return v;
}

// ---------------- banded tsim + norms (unchanged from R5) ----------------
static constexpr int CP = 129;
__global__ __launch_bounds__(256) void k_dots(const float* __restrict__ sim,
                                              const int* __restrict__ tok,
                                              float* __restrict__ dots_raw,
                                              float* __restrict__ normsq) {
  __shared__ float sT[72 * CP];
  __shared__ int stok[72];
  int bx = blockIdx.x, cy = blockIdx.y, tid = threadIdx.x;
  int b = bx >> 4, g0 = (bx & 15) * 64, gidx = b * S + g0;
  if (tid < 72) {
    int p = g0 + tid;
    stok[tid] = (p < S) ? tok[b * S + p] : -1;
  }
  __syncthreads();
  const float4* sim4 = (const float4*)sim;
#pragma unroll
  for (int it = 0; it < 9; ++it) {
    int u = it * 256 + tid, r = u >> 5, q = u & 31;
    int tk = stok[r];
    float4 v = make_float4(0.f, 0.f, 0.f, 0.f);
    if (tk >= 0) v = sim4[(size_t)tk * 2048 + cy * 32 + q];
    float* dst = &sT[r * CP + 4 * q];
    dst[0] = v.x; dst[1] = v.y; dst[2] = v.z; dst[3] = v.w;
  }
  __syncthreads();
  int wave = tid >> 6, lane = tid & 63;
  float acc[9] = {};
  const float* base = &sT[lane * CP + wave * 32];
#pragma unroll 4
  for (int cc = 0; cc < 32; ++cc) {
    float va = base[cc];
    acc[8] += va * va;
#pragma unroll
    for (int o = 1; o <= 8; ++o) acc[o - 1] += va * base[o * CP + cc];
  }
  __syncthreads();
  float* red = sT;
#pragma unroll
  for (int s = 0; s < 9; ++s) red[(wave * 9 + s) * 64 + lane] = acc[s];
  __syncthreads();
  for (int u = tid; u < 576; u += 256) {
    int s = u >> 6, a = u & 63;
    float v = red[s * 64 + a] + red[(9 + s) * 64 + a] +
              red[(18 + s) * 64 + a] + red[(27 + s) * 64 + a];
    if (s < 8) atomicAdd(&dots_raw[(size_t)(gidx + a) * 8 + s], v);
    else       atomicAdd(&normsq[gidx + a], v);
  }
}

// ---------------- fused msc + sem with tanh-at-stage (phases buffer gone) ----------------
static constexpr int CP2 = 132;
__global__ __launch_bounds__(256) void k_coh(const float* __restrict__ emb,
                                             const float* __restrict__ dots_raw,
                                             const float* __restrict__ normsq,
                                             float* __restrict__ msc_raw,
                                             float* __restrict__ semacc) {
  __shared__ float sP[88 * CP2];
  __shared__ float sw2[64 * 17];
  int bx = blockIdx.x, dy = blockIdx.y, tid = threadIdx.x;
  int b = bx >> 4, g0 = (bx & 15) * 64;
  const float4* emb4 = (const float4*)emb;
#pragma unroll
  for (int it = 0; it < 11; ++it) {
    int u = it * 256 + tid, r = u >> 5, q = u & 31;
    int gr = g0 - 8 + r;
    gr = gr < 0 ? 0 : (gr > S - 1 ? S - 1 : gr);
    float4 v = emb4[(size_t)(b * S + gr) * 128 + dy * 32 + q];
    v.x = tanhf(v.x); v.y = tanhf(v.y); v.z = tanhf(v.z); v.w = tanhf(v.w);
    *(float4*)&sP[r * CP2 + 4 * q] = v;
  }
  for (int u = tid; u < 1088; u += 256) {
    int a = u / 17, oi = u - a * 17;
    int i = g0 + a, o = oi - 8, j = i + o;
    int idx = b * S + i;
    float v = 0.f;
    if (j >= 0 && j < S) {
      if (o == 0) v = 1.f;
      else {
        float dr = (o > 0) ? dots_raw[(size_t)idx * 8 + o - 1]
                           : dots_raw[(size_t)(idx + o) * 8 + (-o - 1)];
        float ni = fmaxf(sqrtf(normsq[idx]), 1e-12f);
        float nj = fmaxf(sqrtf(normsq[idx + o]), 1e-12f);
        v = dr / (ni * nj);
      }
    }
    sw2[u] = v;
  }
  __syncthreads();
  int ar = tid >> 2, dq = tid & 3;
  int i = g0 + ar, idx = b * S + i;
  int jmax = S - 1 - i; if (jmax > 15) jmax = 15;
  float swr[17];
#pragma unroll
  for (int oi = 0; oi < 17; ++oi) swr[oi] = sw2[ar * 17 + oi];
  float a0 = 0.f, a1 = 0.f, a2 = 0.f, a3 = 0.f, a4 = 0.f, asem = 0.f;
#pragma unroll 2
  for (int dd = 0; dd < 32; ++dd) {
    int d = dq + 4 * dd;
    const float* pb = &sP[(ar + 8) * CP2 + d];
    float sp = 0.f, sc = 0.f, ss = 0.f;
#pragma unroll
    for (int j = 0; j < 16; ++j) {
      float x = (j <= jmax) ? pb[j * CP2] : 0.f;
      sp += x; sc += __cosf(x); ss += __sinf(x);
      if (j == 0) a0 += __cosf(sp) * sc + __sinf(sp) * ss;
      else if (j == 1)  { float wm = sp * 0.5f;    a1 += __cosf(wm) * (sc * 0.5f)    + __sinf(wm) * (ss * 0.5f); }
      else if (j == 3)  { float wm = sp * 0.25f;   a2 += __cosf(wm) * (sc * 0.25f)   + __sinf(wm) * (ss * 0.25f); }
      else if (j == 7)  { float wm = sp * 0.125f;  a3 += __cosf(wm) * (sc * 0.125f)  + __sinf(wm) * (ss * 0.125f); }
      else if (j == 15) { float wm = sp * 0.0625f; a4 += __cosf(wm) * (sc * 0.0625f) + __sinf(wm) * (ss * 0.0625f); }
    }
    float p0 = pb[0];
    const float* qb = &sP[ar * CP2 + d];
#pragma unroll
    for (int oi = 0; oi < 17; ++oi) {
      int j = i + oi - 8;
      bool valid = (j >= 0) && (j < S);
      float pj = qb[oi * CP2];
      asem += valid ? __cosf((p0 - pj) * swr[oi]) : 0.f;
    }
  }
  a0 = qred(a0); a1 = qred(a1); a2 = qred(a2); a3 = qred(a3); a4 = qred(a4);
  asem = qred(asem);
  if (dq == 0) {
    float* mr = msc_raw + (size_t)idx * 5;
    atomicAdd(mr + 0, a0); atomicAdd(mr + 1, a1); atomicAdd(mr + 2, a2);
    atomicAdd(mr + 3, a3); atomicAdd(mr + 4, a4);
    atomicAdd(semacc + i, asem);
  }
}

// ---------------- weight stage A + cmean (block-switched) ----------------
// 0..255 transpose; 256..511 ctx fold; 512..575 small folds; 576..607 cmean
__global__ __launch_bounds__(256) void k_wbig(const float* __restrict__ W0,
    const float* __restrict__ W1, const float* __restrict__ W2,
    const float* __restrict__ Wf, const float* __restrict__ wctx,
    const float* __restrict__ Wsc, const float* __restrict__ Wsm,
    const float* __restrict__ bsc, const float* __restrict__ bsm,
    const float* __restrict__ bcx, const float* __restrict__ emb,
    const float* __restrict__ mask,
    u16* __restrict__ T0, u16* __restrict__ T1, u16* __restrict__ T2,
    u16* __restrict__ wcatT, float* __restrict__ ctx_acc,
    float* __restrict__ sm_acc, float* __restrict__ cmacc) {
  __shared__ float tile[64][65];
  int blk = blockIdx.x, tid = threadIdx.x;
  if (blk < 256) {
    int z = blk >> 6, rem = blk & 63;
    const float* src = z == 0 ? W0 : z == 1 ? W1 : z == 2 ? W2 : Wf + (size_t)1536 * 512;
    int r0 = (rem >> 3) * 64, c0 = (rem & 7) * 64;
    int tr = tid >> 6, tc = tid & 63;
#pragma unroll 4
    for (int i = 0; i < 16; ++i)
      tile[tr + i * 4][tc] = src[(size_t)(r0 + tr + i * 4) * 512 + c0 + tc];
    __syncthreads();
#pragma unroll 4
    for (int i = 0; i < 16; ++i) {
      int n = c0 + tr + i * 4, k = r0 + tc;
      u16 v = f2bf(tile[tc][tr + i * 4]);
      if (z == 3) wcatT[(size_t)n * KCAT + 512 + k] = v;
      else (z == 0 ? T0 : z == 1 ? T1 : T2)[(size_t)n * 512 + k] = v;
    }
  } else if (blk < 512) {
    int rem = blk - 256;
    int n = (rem & 1) * 256 + tid;
    int kbase = ((rem & 63) >> 1) * 16;
    int j0 = (rem >> 6) * 128;
    float acc[16] = {};
    for (int j = j0; j < j0 + 128; ++j) {
      float wf3 = Wf[(size_t)(1024 + j) * 512 + n];
#pragma unroll
      for (int kk = 0; kk < 16; ++kk) acc[kk] += wctx[(size_t)(kbase + kk) * 512 + j] * wf3;
    }
#pragma unroll
    for (int kk = 0; kk < 16; ++kk)
      atomicAdd(&ctx_acc[(size_t)(kbase + kk) * 512 + n], acc[kk]);
  } else if (blk < 576) {
    int rem = blk - 512;
    int n = (rem & 1) * 256 + tid;
    int j0 = (rem >> 1) * 16;
    float a0 = 0.f, a1 = 0.f, a2 = 0.f, a3 = 0.f, a4 = 0.f, au = 0.f, ac = 0.f;
    for (int j = j0; j < j0 + 16; ++j) {
      float wf1 = Wf[(size_t)j * 512 + n];
      float wf2 = Wf[(size_t)(512 + j) * 512 + n];
      float wf3 = Wf[(size_t)(1024 + j) * 512 + n];
      a0 += Wsc[j] * wf1; a1 += Wsc[512 + j] * wf1; a2 += Wsc[1024 + j] * wf1;
      a3 += Wsc[1536 + j] * wf1; a4 += Wsc[2048 + j] * wf1;
      au += Wsm[j] * wf2;
      ac += bsc[j] * wf1 + bsm[j] * wf2 + bcx[j] * wf3;
    }
    atomicAdd(&sm_acc[0 * 512 + n], a0);
    atomicAdd(&sm_acc[1 * 512 + n], a1);
    atomicAdd(&sm_acc[2 * 512 + n], a2);
    atomicAdd(&sm_acc[3 * 512 + n], a3);
    atomicAdd(&sm_acc[4 * 512 + n], a4);
    atomicAdd(&sm_acc[5 * 512 + n], au);
    atomicAdd(&sm_acc[6 * 512 + n], ac);
  } else {
    int r = blk - 576, b = r >> 3, chunk = r & 7;
    float a0 = 0.f, a1 = 0.f;
    for (int s = chunk * 128; s < chunk * 128 + 128; ++s) {
      float m = mask[b * S + s];
      const float* row = emb + (size_t)(b * S + s) * D;
      a0 += row[tid] * m; a1 += row[tid + 256] * m;
    }
    atomicAdd(cmacc + b * D + tid, a0);
    atomicAdd(cmacc + b * D + tid + 256, a1);
  }
}

// ---------------- Xcat build + ctx pack + small-col finalize (block-switched) ----------------
__global__ __launch_bounds__(256) void k_xcat(const float* __restrict__ emb,
    const float* __restrict__ cmacc, const float* __restrict__ msc_raw,
    const float* __restrict__ semacc, const float* __restrict__ ctx_acc,
    const float* __restrict__ sm_acc, const float* __restrict__ bfu,
    u16* __restrict__ xcat, u16* __restrict__ wcatT) {
  __shared__ float tile[64][65];
  int blk = blockIdx.x, tid = threadIdx.x;
  if (blk < 4096) {
    int idx = blk, b = idx >> 10, i = idx & 1023;
    const float* erow = emb + (size_t)idx * D;
    u16* orow = xcat + (size_t)idx * KCAT;
    for (int c = tid; c < KCAT; c += 256) {
      float v;
      if (c < 512) {
        v = __cosf(erow[c] - cmacc[b * D + c] * (1.f / 1024.f));
      } else if (c < 1024) {
        int d = c - 512;
        v = (i < S - 1) ? __cosf(erow[D + d] - erow[d]) : 0.f;
      } else if (c < 1029) {
        int s = c - 1024, req = (1 << s) - 1;
        v = (S - 1 - i >= req) ? msc_raw[(size_t)idx * 5 + s] * (1.f / 512.f) : 0.f;
      } else if (c == 1029) {
        int cnt = ((i < 8) ? i : 8) + ((S - 1 - i < 8) ? (S - 1 - i) : 8) + 1;
        v = semacc[i] / (4.f * (float)cnt * 512.f);
      } else if (c == 1030) {
        v = 1.f;
      } else v = 0.f;
      orow[c] = f2bf(v);
    }
  } else if (blk < 4160) {
    int rem = blk - 4096;
    int r0 = (rem >> 3) * 64, c0 = (rem & 7) * 64;
    int tr = tid >> 6, tc = tid & 63;
#pragma unroll 4
    for (int i = 0; i < 16; ++i)
      tile[tr + i * 4][tc] = ctx_acc[(size_t)(r0 + tr + i * 4) * 512 + c0 + tc];
    __syncthreads();
#pragma unroll 4
    for (int i = 0; i < 16; ++i)
      wcatT[(size_t)(c0 + tr + i * 4) * KCAT + r0 + tc] = f2bf(tile[tc][tr + i * 4]);
  } else {
    int n = (blk - 4160) * 256 + tid;
    u16* row = wcatT + (size_t)n * KCAT;
#pragma unroll
    for (int s = 0; s < 6; ++s) row[1024 + s] = f2bf(sm_acc[s * 512 + n]);
    row[1030] = f2bf(sm_acc[6 * 512 + n] + bfu[n]);
    for (int k = 1031; k < KCAT; ++k) row[k] = 0;
  }
}

// ---------------- bf16 MFMA GEMM (fuse layer only): C = A @ BT^T ----------------
__global__ __launch_bounds__(256) void k_gemm(const u16* __restrict__ A,
    const u16* __restrict__ BT, float* __restrict__ C, int K) {
  __shared__ __align__(16) u16 sA[64 * 40];
  __shared__ __align__(16) u16 sB[64 * 40];
  int tid = threadIdx.x, wave = tid >> 6, lane = tid & 63;
  int m0 = blockIdx.x * 64, n0 = blockIdx.y * 64;
  int lr = tid >> 2, lc = (tid & 3) * 8;
  int q8 = (lane >> 4) * 8, l15 = lane & 15;
  const u16* Ap = A + (size_t)(m0 + lr) * K + lc;
  const u16* Bp = BT + (size_t)(n0 + lr) * K + lc;
  f32x4 acc[4] = {};
  for (int k0 = 0; k0 < K; k0 += 32) {
    *(uint4*)&sA[lr * 40 + lc] = *(const uint4*)(Ap + k0);
    *(uint4*)&sB[lr * 40 + lc] = *(const uint4*)(Bp + k0);
    __syncthreads();
    bf16x8 af = *(const bf16x8*)&sA[(wave * 16 + l15) * 40 + q8];
#pragma unroll
    for (int f = 0; f < 4; ++f) {
      bf16x8 bfr = *(const bf16x8*)&sB[(f * 16 + l15) * 40 + q8];
      acc[f] = __builtin_amdgcn_mfma_f32_16x16x32_bf16(af, bfr, acc[f], 0, 0, 0);
    }
    __syncthreads();
  }
  int r0 = m0 + wave * 16 + (lane >> 4) * 4;
#pragma unroll
  for (int f = 0; f < 4; ++f) {
    int col = n0 + f * 16 + l15;
#pragma unroll
    for (int r = 0; r < 4; ++r)
      C[(size_t)(r0 + r) * 512 + col] = acc[f][r];
  }
}

// ---------------- post-fuse: x = gelu(LN1(y1)) ----------------
__global__ __launch_bounds__(256) void k_post_y1(const float* __restrict__ y,
    float* __restrict__ x, const float* __restrict__ g1, const float* __restrict__ b1) {
  __shared__ float sm[8];
  int row = blockIdx.x, tid = threadIdx.x;
  size_t base = (size_t)row * 512;
  float v0 = y[base + tid], v1 = y[base + tid + 256];
  float s = v0 + v1, ss = v0 * v0 + v1 * v1;
  bred2(s, ss, sm, tid);
  float m = s * (1.f / 512.f);
  float inv = rsqrtf(ss * (1.f / 512.f) - m * m + 1e-5f);
  x[base + tid] = gelu((v0 - m) * inv * g1[tid] + b1[tid]);
  x[base + tid + 256] = gelu((v1 - m) * inv * g1[tid + 256] + b1[tid + 256]);
}

// ---------------- fused residual stack: 3x (LN2 -> GEMM -> +0.1*gelu) -> LN3 ----------------
// grid 128, block 256 (4 waves). Block owns rows r0..r0+31, wave w owns cols
// w*128..+127. x in C-layout registers; t bf16 in LDS; B streamed from L2.
__global__ __launch_bounds__(256) void k_resnet(const float* __restrict__ xin,
    const u16* __restrict__ W0, const u16* __restrict__ W1, const u16* __restrict__ W2,
    const float* __restrict__ be0, const float* __restrict__ be1, const float* __restrict__ be2,
    const float* __restrict__ g2, const float* __restrict__ b2v,
    const float* __restrict__ g3, const float* __restrict__ b3v,
    float* __restrict__ out) {
  __shared__ u16 tl[32 * 520];
  __shared__ float rsm[4][32][2];
  int tid = threadIdx.x, wave = tid >> 6, lane = tid & 63;
  int q = lane >> 4, l15 = lane & 15, q8 = q * 8;
  int r0 = blockIdx.x * 32, ncol = wave * 128;
  float xr[2][8][4];
  float g2c[8], b2c[8];
#pragma unroll
  for (int f = 0; f < 8; ++f) {
    int col = ncol + f * 16 + l15;
    g2c[f] = g2[col]; b2c[f] = b2v[col];
#pragma unroll
    for (int mf = 0; mf < 2; ++mf)
#pragma unroll
      for (int r = 0; r < 4; ++r)
        xr[mf][f][r] = xin[(size_t)(r0 + mf * 16 + q * 4 + r) * 512 + col];
  }
  const u16* Wt[3] = {W0, W1, W2};
  const float* bet[3] = {be0, be1, be2};
#pragma unroll 1
  for (int L = 0; L < 4; ++L) {
    // --- row stats (sum, sumsq) over 512 cols ---
    float s[2][4], ss[2][4];
#pragma unroll
    for (int mf = 0; mf < 2; ++mf)
#pragma unroll
      for (int r = 0; r < 4; ++r) {
        float a = 0.f, b = 0.f;
#pragma unroll
        for (int f = 0; f < 8; ++f) { float v = xr[mf][f][r]; a += v; b += v * v; }
#pragma unroll
        for (int m = 8; m; m >>= 1) { a += __shfl_xor(a, m, 64); b += __shfl_xor(b, m, 64); }
        s[mf][r] = a; ss[mf][r] = b;
      }
    if (l15 == 0) {
#pragma unroll
      for (int mf = 0; mf < 2; ++mf)
#pragma unroll
        for (int r = 0; r < 4; ++r) {
          rsm[wave][mf * 16 + q * 4 + r][0] = s[mf][r];
          rsm[wave][mf * 16 + q * 4 + r][1] = ss[mf][r];
        }
    }
    __syncthreads();
    float mean[2][4], inv[2][4];
#pragma unroll
    for (int mf = 0; mf < 2; ++mf)
#pragma unroll
      for (int r = 0; r < 4; ++r) {
        int row = mf * 16 + q * 4 + r;
        float su = rsm[0][row][0] + rsm[1][row][0] + rsm[2][row][0] + rsm[3][row][0];
        float sq = rsm[0][row][1] + rsm[1][row][1] + rsm[2][row][1] + rsm[3][row][1];
        float m = su * (1.f / 512.f);
        mean[mf][r] = m;
        inv[mf][r] = rsqrtf(sq * (1.f / 512.f) - m * m + 1e-5f);
      }
    if (L == 3) {
#pragma unroll
      for (int mf = 0; mf < 2; ++mf)
#pragma unroll
        for (int f = 0; f < 8; ++f) {
          int col = ncol + f * 16 + l15;
          float gg = g3[col], bb = b3v[col];
#pragma unroll
          for (int r = 0; r < 4; ++r)
            out[(size_t)(r0 + mf * 16 + q * 4 + r) * 512 + col] =
                (xr[mf][f][r] - mean[mf][r]) * inv[mf][r] * gg + bb;
        }
      return;
    }
    // --- t = bf16(LN2(x)) into LDS ---
#pragma unroll
    for (int mf = 0; mf < 2; ++mf)
#pragma unroll
      for (int f = 0; f < 8; ++f) {
        int col = ncol + f * 16 + l15;
#pragma unroll
        for (int r = 0; r < 4; ++r)
          tl[(mf * 16 + q * 4 + r) * 520 + col] =
              f2bf((xr[mf][f][r] - mean[mf][r]) * inv[mf][r] * g2c[f] + b2c[f]);
      }
    __syncthreads();
    // --- GEMM: h = t @ W^T, B streamed from L2 ---
    const u16* W = Wt[L];
    f32x4 acc[2][8] = {};
    for (int k0 = 0; k0 < 512; k0 += 32) {
      bf16x8 af0 = *(const bf16x8*)&tl[l15 * 520 + k0 + q8];
      bf16x8 af1 = *(const bf16x8*)&tl[(16 + l15) * 520 + k0 + q8];
#pragma unroll
      for (int f = 0; f < 8; ++f) {
        bf16x8 bfr = *(const bf16x8*)(W + (size_t)(ncol + f * 16 + l15) * 512 + k0 + q8);
        acc[0][f] = __builtin_amdgcn_mfma_f32_16x16x32_bf16(af0, bfr, acc[0][f], 0, 0, 0);
        acc[1][f] = __builtin_amdgcn_mfma_f32_16x16x32_bf16(af1, bfr, acc[1][f], 0, 0, 0);
      }
    }
    __syncthreads();   // all waves done reading tl before next layer rewrites
    // --- residual update ---
    const float* be = bet[L];
#pragma unroll
    for (int f = 0; f < 8; ++f) {
      int col = ncol + f * 16 + l15;
      float bv = be[col];
#pragma unroll
      for (int mf = 0; mf < 2; ++mf)
#pragma unroll
        for (int r = 0; r < 4; ++r)
          xr[mf][f][r] += 0.1f * gelu(acc[mf][f][r] + bv);
    }
  }
}

// ---------------------------------------------------------------------------
extern "C" void kernel_launch(void* const* d_in, const int* in_sizes, int n_in,
                              void* d_out, int out_size, void* d_ws, size_t ws_size,
                              hipStream_t stream) {
  const float* emb     = (const float*)d_in[0];
  const int*   tok     = (const int*)d_in[1];
  const float* mask    = (const float*)d_in[2];
  const float* sim     = (const float*)d_in[3];
  const float* W_scale = (const float*)d_in[4];
  const float* b_scale = (const float*)d_in[5];
  const float* W_sem   = (const float*)d_in[6];
  const float* b_sem   = (const float*)d_in[7];
  const float* W_ctx   = (const float*)d_in[8];
  const float* b_ctx   = (const float*)d_in[9];
  const float* W_fuse  = (const float*)d_in[10];
  const float* b_fuse  = (const float*)d_in[11];
  const float* ln1_g = (const float*)d_in[12], *ln1_b = (const float*)d_in[13];
  const float* ln2_g = (const float*)d_in[14], *ln2_b = (const float*)d_in[15];
  const float* ln3_g = (const float*)d_in[16], *ln3_b = (const float*)d_in[17];
  const float* W_e0 = (const float*)d_in[18], *b_e0 = (const float*)d_in[19];
  const float* W_e1 = (const float*)d_in[20], *b_e1 = (const float*)d_in[21];
  const float* W_e2 = (const float*)d_in[22], *b_e2 = (const float*)d_in[23];
  float* out = (float*)d_out;

  char* w = (char*)d_ws; size_t off = 0;
  auto alloc = [&](size_t bytes) { void* p = w + off; off += (bytes + 255) & ~(size_t)255; return p; };
  float* hbuf   = (float*)alloc((size_t)4096 * 512 * 4);
  float* xbuf   = (float*)alloc((size_t)4096 * 512 * 4);
  u16*   xcat   = (u16*)  alloc((size_t)4096 * KCAT * 2);
  u16*   wcatT  = (u16*)  alloc((size_t)512 * KCAT * 2);
  u16*   We0T   = (u16*)  alloc((size_t)512 * 512 * 2);
  u16*   We1T   = (u16*)  alloc((size_t)512 * 512 * 2);
  u16*   We2T   = (u16*)  alloc((size_t)512 * 512 * 2);
  // zero-init cluster (contiguous, sizes multiples of 256 B: one memset)
  float* semacc   = (float*)alloc((size_t)1024 * 4);
  float* cmacc    = (float*)alloc((size_t)4 * 512 * 4);
  float* dots_raw = (float*)alloc((size_t)4096 * 8 * 4);
  float* normsq   = (float*)alloc((size_t)4096 * 4);
  float* msc_raw  = (float*)alloc((size_t)4096 * 5 * 4);
  float* ctx_acc  = (float*)alloc((size_t)512 * 512 * 4);
  float* sm_acc   = (float*)alloc((size_t)7 * 512 * 4);
  (void)ws_size; (void)in_sizes; (void)n_in; (void)out_size;

  size_t zbytes = (size_t)(1024 + 4 * 512 + 4096 * 8 + 4096 + 4096 * 5 + 512 * 512 + 7 * 512) * 4;
  hipMemsetAsync(semacc, 0, zbytes, stream);

  k_dots<<<dim3(64, 64), 256, 0, stream>>>(sim, tok, dots_raw, normsq);
  k_wbig<<<608, 256, 0, stream>>>(W_e0, W_e1, W_e2, W_fuse, W_ctx,
                                  W_scale, W_sem, b_scale, b_sem, b_ctx, emb, mask,
                                  We0T, We1T, We2T, wcatT, ctx_acc, sm_acc, cmacc);
  k_coh<<<dim3(64, 4), 256, 0, stream>>>(emb, dots_raw, normsq, msc_raw, semacc);
  k_xcat<<<4162, 256, 0, stream>>>(emb, cmacc, msc_raw, semacc, ctx_acc, sm_acc,
                                   b_fuse, xcat, wcatT);
  k_gemm<<<dim3(64, 8), 256, 0, stream>>>(xcat, wcatT, hbuf, KCAT);
  k_post_y1<<<4096, 256, 0, stream>>>(hbuf, xbuf, ln1_g, ln1_b);
  k_resnet<<<128, 256, 0, stream>>>(xbuf, We0T, We1T, We2T, b_e0, b_e1, b_e2,
                                    ln2_g, ln2_b, ln3_g, ln3_b, out);
}